// Round 3
// baseline (7535.794 us; speedup 1.0000x reference)
//
#include <hip/hip_runtime.h>
#include <hip/hip_cooperative_groups.h>

namespace cg = cooperative_groups;

typedef unsigned short u16;
typedef __attribute__((ext_vector_type(8))) short short8;
typedef __attribute__((ext_vector_type(4))) float f32x4;
typedef float float4a __attribute__((ext_vector_type(4), aligned(4)));

#define T_ 70
#define B_ 80
#define V_ 33278
#define E_ 400
#define H_ 1150
#define EP 416      // 400 padded to K-mult of 32
#define HP 1152     // 1150 padded
#define G1 4600     // 4*H
#define G1P 4608
#define G3 1600     // 4*E
#define VP 33280    // 260*128
#define M_ 5600     // T*B
#define MP 5632     // 44*128

__device__ __forceinline__ u16 f2bf(float f) {
  unsigned u = __builtin_bit_cast(unsigned, f);
  u = (u + 0x7fffu + ((u >> 16) & 1u)) >> 16;   // round-to-nearest-even
  return (u16)u;
}

__device__ __forceinline__ void gload16(const void* g, void* l) {
  __builtin_amdgcn_global_load_lds((const __attribute__((address_space(1))) void*)g,
                                   (__attribute__((address_space(3))) void*)l, 16, 0, 0);
}

// ---------------- prep kernels ----------------

__global__ void zero_k(float4* p, long n4) {
  long i = (long)blockIdx.x * blockDim.x + threadIdx.x;
  long stride = (long)gridDim.x * blockDim.x;
  float4 z = {0.f, 0.f, 0.f, 0.f};
  for (; i < n4; i += stride) p[i] = z;
}

__global__ void convert_pad(const float* __restrict__ src, u16* __restrict__ dst,
                            int R, int C, int Cp) {
  int c = blockIdx.x * 256 + threadIdx.x;
  int r = blockIdx.y;
  if (c < Cp) {
    float v = (r < R && c < C) ? src[(size_t)r * C + c] : 0.f;
    dst[(size_t)r * Cp + c] = f2bf(v);
  }
}

__global__ void embed_k(const int* __restrict__ ids, const float* __restrict__ We,
                        u16* __restrict__ x) {
  int r = blockIdx.x;                 // 0..5599
  int tok = ids[r];
  const float* s = We + (size_t)tok * E_;
  u16* d = x + (size_t)r * EP;
  for (int j = threadIdx.x; j < E_; j += 256) d[j] = f2bf(s[j]);
}

__global__ void stinit_k(const float* __restrict__ s, u16* __restrict__ dst, int H, int Kp) {
  int i = blockIdx.x * 256 + threadIdx.x;
  if (i < B_ * Kp) {
    int r = i / Kp, j = i - r * Kp;
    dst[i] = f2bf(j < H ? s[r * H + j] : 0.f);
  }
}

__global__ void cpy_k(float* __restrict__ d, const float* __restrict__ s, int n) {
  int i = blockIdx.x * 256 + threadIdx.x;
  if (i < n) d[i] = s[i];
}

__global__ void badd_k(float* __restrict__ d, const float* __restrict__ a,
                       const float* __restrict__ b, int n) {
  int i = blockIdx.x * 256 + threadIdx.x;
  if (i < n) d[i] = a[i] + b[i];
}

// ---------------- big GEMM: C[M][ldc] = A * B^T (+bias) ----------------
// Flat 1-D grid, bm FAST (concurrent blocks share a bn window -> B L2-resident).
// LDS-transposed epilogue: 16-consecutive-float stores per lane (full-line writes).
__global__ __launch_bounds__(256) void gemm_bt2(
    const u16* __restrict__ A, const u16* __restrict__ B,
    float* __restrict__ C, const float* __restrict__ bias,
    int M, int Nstore, int Kp, long ldc, int MT)
{
  __shared__ u16 lA[128 * 32];
  __shared__ u16 lB[128 * 32];
  __shared__ float st[2][16][132];
  __shared__ float bsh[128];
  const int tid = threadIdx.x;
  const int bid = blockIdx.x;
  const int bm = bid % MT, bn = bid / MT;
  const int KS = Kp >> 5;
  const int wid = tid >> 6, lane = tid & 63;
  const int wq = wid >> 1;                 // row group 0/1
  const int wm = wq << 6, wn = (wid & 1) << 6;
  const int lr = lane & 15, lk = lane >> 4;
  if (tid < 128) {
    int gc = bn * 128 + tid;
    bsh[tid] = (bias && gc < Nstore) ? bias[gc] : 0.f;
  }
  f32x4 acc[4][4] = {};
  const u16* Ab = A + (size_t)bm * 128 * Kp;
  const u16* Bb = B + (size_t)bn * 128 * Kp;
  const int sr = tid >> 2;
  const int sc = (tid & 3) << 3;
  for (int ks = 0; ks < KS; ++ks) {
    const int k0 = ks << 5;
    gload16(Ab + (size_t)sr * Kp + k0 + sc, &lA[tid * 8]);
    gload16(Ab + (size_t)(sr + 64) * Kp + k0 + sc, &lA[2048 + tid * 8]);
    gload16(Bb + (size_t)sr * Kp + k0 + sc, &lB[tid * 8]);
    gload16(Bb + (size_t)(sr + 64) * Kp + k0 + sc, &lB[2048 + tid * 8]);
    __syncthreads();
    short8 av[4], bv[4];
#pragma unroll
    for (int mi = 0; mi < 4; ++mi)
      av[mi] = *(const short8*)&lA[(wm + mi * 16 + lr) * 32 + lk * 8];
#pragma unroll
    for (int ni = 0; ni < 4; ++ni)
      bv[ni] = *(const short8*)&lB[(wn + ni * 16 + lr) * 32 + lk * 8];
#pragma unroll
    for (int mi = 0; mi < 4; ++mi)
#pragma unroll
      for (int ni = 0; ni < 4; ++ni)
        acc[mi][ni] = __builtin_amdgcn_mfma_f32_16x16x32_bf16(av[mi], bv[ni], acc[mi][ni], 0, 0, 0);
    __syncthreads();
  }
  // epilogue: stage 32x128 slab per mi, store coalesced rows
  const int rgrp = tid >> 7, srow = (tid >> 3) & 15, cq = tid & 7;
#pragma unroll
  for (int mi = 0; mi < 4; ++mi) {
#pragma unroll
    for (int ni = 0; ni < 4; ++ni)
#pragma unroll
      for (int r = 0; r < 4; ++r)
        st[wq][lk * 4 + r][wn + ni * 16 + lr] = acc[mi][ni][r];
    __syncthreads();
    const int gr = bm * 128 + rgrp * 64 + mi * 16 + srow;
    if (gr < M) {
      const int gcb = bn * 128 + cq * 16;
      float* dst = &C[(size_t)gr * ldc + gcb];
      if (gcb + 15 < Nstore) {
#pragma unroll
        for (int q = 0; q < 4; ++q) {
          float4a v;
#pragma unroll
          for (int e = 0; e < 4; ++e)
            v[e] = st[rgrp][srow][cq * 16 + q * 4 + e] + bsh[cq * 16 + q * 4 + e];
          *(float4a*)(dst + q * 4) = v;
        }
      } else {
        for (int e = 0; e < 16; ++e)
          if (gcb + e < Nstore)
            dst[e] = st[rgrp][srow][cq * 16 + e] + bsh[cq * 16 + e];
      }
    }
    __syncthreads();
  }
}

// ---------------- persistent pipelined recurrence (cooperative) ----------------
// 169 blocks x 512 thr. blk<72: layer1 j-tile; <144: layer2; else layer3.
// Step s: layer1 t=s, layer2 t=s-1, layer3 t=s-2. grid.sync() between steps.
struct RecArgs {
  const float* xg1;
  const u16 *Whh1, *Wih2, *Whh2, *Wih3, *Whh3;
  const u16 *h1i, *h2i, *h3i;
  u16 *h1a, *h2a, *h3a;
  const float *b1, *b2, *b3;
  float *c1, *c2, *c3, *h1s, *h2s, *h3s;
};

__global__ __launch_bounds__(512) void lstm_rec(RecArgs A) {
  cg::grid_group grid = cg::this_grid();
  __shared__ float gl[B_ * 64];
  const int blk = blockIdx.x;
  const int tid = threadIdx.x;
  const int wid = tid >> 6, lane = tid & 63;
  const int lr = lane & 15, lk = lane >> 4;
  int layer, jblk;
  if (blk < 72)       { layer = 0; jblk = blk; }
  else if (blk < 144) { layer = 1; jblk = blk - 72; }
  else                { layer = 2; jblk = blk - 144; }
  const int j0 = jblk << 4;

  for (int s = 0; s < 72; ++s) {
    int t; bool active;
    const u16 *Wa = nullptr, *Xa = nullptr, *Wb = nullptr, *Xb = nullptr;
    const float *xg = nullptr, *bb = nullptr;
    float *cb_ = nullptr, *hs_ = nullptr; u16* ho_ = nullptr;
    int Kpa = 0, KSa = 0, Kpb = 0, KSb = 0, H = 0, Kpo = 0;
    if (layer == 0) {
      t = s; active = (t < T_);
      if (active) {
        xg = A.xg1 + (size_t)t * B_ * G1P;
        Wa = A.Whh1; Xa = t ? A.h1a + (size_t)(t - 1) * B_ * HP : A.h1i;
        Kpa = HP; KSa = HP / 32; KSb = 0;
        bb = A.b1; cb_ = A.c1; hs_ = A.h1s;
        ho_ = A.h1a + (size_t)t * B_ * HP; H = H_; Kpo = HP;
      }
    } else if (layer == 1) {
      t = s - 1; active = (s >= 1 && t < T_);
      if (active) {
        Wa = A.Whh2; Xa = t ? A.h2a + (size_t)(t - 1) * B_ * HP : A.h2i;
        Kpa = HP; KSa = HP / 32;
        Wb = A.Wih2; Xb = A.h1a + (size_t)t * B_ * HP;
        Kpb = HP; KSb = HP / 32;
        bb = A.b2; cb_ = A.c2; hs_ = A.h2s;
        ho_ = A.h2a + (size_t)t * B_ * HP; H = H_; Kpo = HP;
      }
    } else {
      t = s - 2; active = (s >= 2);
      if (active) {
        Wa = A.Whh3; Xa = t ? A.h3a + (size_t)(t - 1) * B_ * EP : A.h3i;
        Kpa = EP; KSa = EP / 32;
        Wb = A.Wih3; Xb = A.h2a + (size_t)t * B_ * HP;
        Kpb = HP; KSb = HP / 32;
        bb = A.b3; cb_ = A.c3; hs_ = A.h3s;
        ho_ = A.h3a + (size_t)t * B_ * EP; H = E_; Kpo = EP;
      }
    }
    if (active) {
      for (int i = tid; i < B_ * 64; i += 512) gl[i] = 0.f;
      __syncthreads();
      const int KSt = KSa + KSb;
      const int gs0 = (wid * KSt) >> 3, gs1 = ((wid + 1) * KSt) >> 3;
      f32x4 acc[5][4] = {};
      for (int gs = gs0; gs < gs1; ++gs) {
        const u16* Wp; const u16* Xp; int Kp, k0;
        if (gs < KSa) { Wp = Wa; Xp = Xa; Kp = Kpa; k0 = gs << 5; }
        else          { Wp = Wb; Xp = Xb; Kp = Kpb; k0 = (gs - KSa) << 5; }
        const int kk = k0 + (lk << 3);
        short8 av[5], bv[4];
#pragma unroll
        for (int mf = 0; mf < 5; ++mf)
          av[mf] = *(const short8*)&Xp[(size_t)(mf * 16 + lr) * Kp + kk];
#pragma unroll
        for (int g = 0; g < 4; ++g)
          bv[g] = *(const short8*)&Wp[(size_t)(g * H + j0 + lr) * Kp + kk];
#pragma unroll
        for (int mf = 0; mf < 5; ++mf)
#pragma unroll
          for (int g = 0; g < 4; ++g)
            acc[mf][g] = __builtin_amdgcn_mfma_f32_16x16x32_bf16(av[mf], bv[g], acc[mf][g], 0, 0, 0);
      }
#pragma unroll
      for (int mf = 0; mf < 5; ++mf)
#pragma unroll
        for (int g = 0; g < 4; ++g)
#pragma unroll
          for (int r = 0; r < 4; ++r)
            atomicAdd(&gl[(mf * 16 + lk * 4 + r) * 64 + g * 16 + lr], acc[mf][g][r]);
      __syncthreads();
      for (int i = tid; i < B_ * 16; i += 512) {
        const int row = i >> 4, jj = i & 15, j = j0 + jj;
        if (j < H) {
          const float* xr = xg ? xg + (size_t)row * G1P : nullptr;
          float vi = gl[row * 64 + jj]      + (xr ? xr[j]         : 0.f) + bb[j];
          float vf = gl[row * 64 + 16 + jj] + (xr ? xr[H + j]     : 0.f) + bb[H + j];
          float vg = gl[row * 64 + 32 + jj] + (xr ? xr[2 * H + j] : 0.f) + bb[2 * H + j];
          float vo = gl[row * 64 + 48 + jj] + (xr ? xr[3 * H + j] : 0.f) + bb[3 * H + j];
          float si = 1.f / (1.f + __expf(-vi));
          float sf = 1.f / (1.f + __expf(-vf));
          float tg = tanhf(vg);
          float so = 1.f / (1.f + __expf(-vo));
          float c = sf * cb_[row * H + j] + si * tg;
          cb_[row * H + j] = c;
          float h = so * tanhf(c);
          hs_[row * H + j] = h;
          ho_[(size_t)row * Kpo + j] = f2bf(h);
        }
      }
    }
    grid.sync();
  }
}

// ---------------- final-state copy into d_out tail ----------------
__global__ void tail_k(const float* __restrict__ h1, const float* __restrict__ c1,
                       const float* __restrict__ h2, const float* __restrict__ c2,
                       const float* __restrict__ h3, const float* __restrict__ c3,
                       float* __restrict__ out) {
  int i = blockIdx.x * 256 + threadIdx.x;
  const long base = (long)M_ * V_;
  if (i < 92000)       out[base + i] = h1[i];
  else if (i < 184000) out[base + i] = c1[i - 92000];
  else if (i < 276000) out[base + i] = h2[i - 184000];
  else if (i < 368000) out[base + i] = c2[i - 276000];
  else if (i < 400000) out[base + i] = h3[i - 368000];
  else if (i < 432000) out[base + i] = c3[i - 400000];
}

// ---------------- host ----------------

extern "C" void kernel_launch(void* const* d_in, const int* in_sizes, int n_in,
                              void* d_out, int out_size, void* d_ws, size_t ws_size,
                              hipStream_t stream)
{
  const int*   ids  = (const int*)d_in[0];
  const float* s1h  = (const float*)d_in[1];
  const float* s1c  = (const float*)d_in[2];
  const float* s2h  = (const float*)d_in[3];
  const float* s2c  = (const float*)d_in[4];
  const float* s3h  = (const float*)d_in[5];
  const float* s3c  = (const float*)d_in[6];
  const float* Wemb = (const float*)d_in[7];
  const float* fcb  = (const float*)d_in[8];
  const float* Wih1 = (const float*)d_in[9];
  const float* Whh1 = (const float*)d_in[10];
  const float* bih1 = (const float*)d_in[11];
  const float* bhh1 = (const float*)d_in[12];
  const float* Wih2 = (const float*)d_in[13];
  const float* Whh2 = (const float*)d_in[14];
  const float* bih2 = (const float*)d_in[15];
  const float* bhh2 = (const float*)d_in[16];
  const float* Wih3 = (const float*)d_in[17];
  const float* Whh3 = (const float*)d_in[18];
  const float* bih3 = (const float*)d_in[19];
  const float* bhh3 = (const float*)d_in[20];
  float* out = (float*)d_out;

  char* p = (char*)d_ws;
  auto alloc = [&](size_t bytes) -> char* {
    char* r = p; p += (bytes + 255) & ~(size_t)255; return r;
  };
  u16* WembP = (u16*)alloc((size_t)VP * EP * 2);
  u16* Wih1P = (u16*)alloc((size_t)G1P * EP * 2);
  u16* Whh1P = (u16*)alloc((size_t)G1P * HP * 2);
  u16* Wih2P = (u16*)alloc((size_t)G1P * HP * 2);
  u16* Whh2P = (u16*)alloc((size_t)G1P * HP * 2);
  u16* Wih3P = (u16*)alloc((size_t)G3 * HP * 2);
  u16* Whh3P = (u16*)alloc((size_t)G3 * EP * 2);
  char* zs = p;  // ---- start of zero-initialized region ----
  u16* xb  = (u16*)alloc((size_t)MP * EP * 2);
  u16* h1a = (u16*)alloc((size_t)MP * HP * 2);
  u16* h2a = (u16*)alloc((size_t)MP * HP * 2);
  u16* h3a = (u16*)alloc((size_t)MP * EP * 2);
  u16* h1i = (u16*)alloc((size_t)B_ * HP * 2);
  u16* h2i = (u16*)alloc((size_t)B_ * HP * 2);
  u16* h3i = (u16*)alloc((size_t)B_ * EP * 2);
  char* ze = p;  // ---- end of zero region ----
  float* xg1 = (float*)alloc((size_t)M_ * G1P * 4);
  float* c1  = (float*)alloc((size_t)B_ * H_ * 4);
  float* c2  = (float*)alloc((size_t)B_ * H_ * 4);
  float* c3  = (float*)alloc((size_t)B_ * E_ * 4);
  float* h1s = (float*)alloc((size_t)B_ * H_ * 4);
  float* h2s = (float*)alloc((size_t)B_ * H_ * 4);
  float* h3s = (float*)alloc((size_t)B_ * E_ * 4);
  float* b1  = (float*)alloc((size_t)G1 * 4);
  float* b2  = (float*)alloc((size_t)G1 * 4);
  float* b3  = (float*)alloc((size_t)G3 * 4);
  (void)ws_size; (void)in_sizes; (void)n_in; (void)out_size;

  long zn4 = (long)((ze - zs) >> 4);
  zero_k<<<dim3(2048), dim3(256), 0, stream>>>((float4*)zs, zn4);

  convert_pad<<<dim3(2, VP), dim3(256), 0, stream>>>(Wemb, WembP, V_, E_, EP);
  convert_pad<<<dim3(2, G1P), dim3(256), 0, stream>>>(Wih1, Wih1P, G1, E_, EP);
  convert_pad<<<dim3(5, G1P), dim3(256), 0, stream>>>(Whh1, Whh1P, G1, H_, HP);
  convert_pad<<<dim3(5, G1P), dim3(256), 0, stream>>>(Wih2, Wih2P, G1, H_, HP);
  convert_pad<<<dim3(5, G1P), dim3(256), 0, stream>>>(Whh2, Whh2P, G1, H_, HP);
  convert_pad<<<dim3(5, G3), dim3(256), 0, stream>>>(Wih3, Wih3P, G3, H_, HP);
  convert_pad<<<dim3(2, G3), dim3(256), 0, stream>>>(Whh3, Whh3P, G3, E_, EP);

  embed_k<<<dim3(M_), dim3(256), 0, stream>>>(ids, Wemb, xb);
  stinit_k<<<dim3(360), dim3(256), 0, stream>>>(s1h, h1i, H_, HP);
  stinit_k<<<dim3(360), dim3(256), 0, stream>>>(s2h, h2i, H_, HP);
  stinit_k<<<dim3(130), dim3(256), 0, stream>>>(s3h, h3i, E_, EP);
  cpy_k<<<dim3(360), dim3(256), 0, stream>>>(c1, s1c, B_ * H_);
  cpy_k<<<dim3(360), dim3(256), 0, stream>>>(c2, s2c, B_ * H_);
  cpy_k<<<dim3(125), dim3(256), 0, stream>>>(c3, s3c, B_ * E_);
  badd_k<<<dim3(18), dim3(256), 0, stream>>>(b1, bih1, bhh1, G1);
  badd_k<<<dim3(18), dim3(256), 0, stream>>>(b2, bih2, bhh2, G1);
  badd_k<<<dim3(7), dim3(256), 0, stream>>>(b3, bih3, bhh3, G3);

  // xg1 = x @ Wih1^T   (flat grid, bm fast)
  gemm_bt2<<<dim3(44 * 36), dim3(256), 0, stream>>>(
      xb, Wih1P, xg1, nullptr, M_, G1P, EP, (long)G1P, 44);

  // persistent pipelined recurrence (single cooperative launch)
  RecArgs ra;
  ra.xg1 = xg1;
  ra.Whh1 = Whh1P; ra.Wih2 = Wih2P; ra.Whh2 = Whh2P; ra.Wih3 = Wih3P; ra.Whh3 = Whh3P;
  ra.h1i = h1i; ra.h2i = h2i; ra.h3i = h3i;
  ra.h1a = h1a; ra.h2a = h2a; ra.h3a = h3a;
  ra.b1 = b1; ra.b2 = b2; ra.b3 = b3;
  ra.c1 = c1; ra.c2 = c2; ra.c3 = c3;
  ra.h1s = h1s; ra.h2s = h2s; ra.h3s = h3s;
  void* kp[] = { &ra };
  hipLaunchCooperativeKernel((const void*)lstm_rec, dim3(169), dim3(512), kp, 0, stream);

  // scores = h3_all @ W_emb^T + fc_b  -> d_out  (flat grid, bm fast)
  gemm_bt2<<<dim3(44 * 260), dim3(256), 0, stream>>>(
      h3a, WembP, out, fcb, M_, V_, EP, (long)V_, 44);
  tail_k<<<dim3(1688), dim3(256), 0, stream>>>(h1s, c1, h2s, c2, h3s, c3, out);
}